// Round 1
// 161.553 us; speedup vs baseline: 1.1255x; 1.1255x over previous
//
#include <hip/hip_runtime.h>
#include <math.h>

#define NSEQ 2048
#define CDIM 768
#define NH   12
#define HD   64
#define NB   2

typedef unsigned short u16;
typedef __attribute__((ext_vector_type(8))) short bf16x8;   // 8 bf16 = 4 VGPRs
typedef __attribute__((ext_vector_type(4))) float f32x4;
typedef __attribute__((ext_vector_type(8))) float f32x8;
typedef __attribute__((ext_vector_type(4))) __bf16 bf16x4t;
typedef __attribute__((ext_vector_type(8))) __bf16 bf16x8t;

// fp32 -> bf16 round-to-nearest-even (scalar epilogue paths)
__device__ __forceinline__ u16 f2bf(float x) {
    unsigned int u = __float_as_uint(x);
    u += 0x7fffu + ((u >> 16) & 1u);
    return (u16)(u >> 16);
}

// pack 8 fp32 -> 8 bf16 via compiler-generated v_cvt_pk_bf16_f32 (4 instrs,
// was ~24 VALU of manual bit-twiddle f2bf — the qkv staging was VALU-bound)
__device__ __forceinline__ uint4 pack8(float4 a, float4 b) {
    f32x8 v = {a.x, a.y, a.z, a.w, b.x, b.y, b.z, b.w};
    union { bf16x8t t; uint4 u; } o;
    o.t = __builtin_convertvector(v, bf16x8t);
    return o.u;
}

#define LSTR 72   // LDS row stride (u16) for the GEMM kernels (+8 pad)

// async global->LDS, 16B per lane, LDS dest = wave-uniform base + lane*16
#define GLD16(gp, lp) __builtin_amdgcn_global_load_lds( \
    (__attribute__((address_space(1))) void*)(const void*)(gp), \
    (__attribute__((address_space(3))) void*)(void*)(lp), 16, 0, 0)

// ---------------------------------------------------------------------------
// Kernel 1: qkv = X @ Wqkv^T, bf16 MFMA, fp32 inputs converted in-register
// during staging. Tiles 128x128x64, 4 waves 2x2, register-prefetch staging,
// LDS epilogue with full-128B-line stores. Fused scale (q), RoPE (q,k).
// Q,K: [B,H,N,64]; V: [B,H,64,N] (transposed for attn B-fragments).
// ---------------------------------------------------------------------------
__global__ __launch_bounds__(256)
void qkv_mfma_kernel(const float* __restrict__ Xf, const float* __restrict__ Wf,
                     u16* __restrict__ Qb, u16* __restrict__ Kb,
                     u16* __restrict__ Vb)
{
    __shared__ __align__(16) u16 S[2 * 128 * LSTR];
    u16* As = S;
    u16* Bs = S + 128 * LSTR;

    const int tid  = threadIdx.x;
    const int lane = tid & 63;
    const int wid  = tid >> 6;
    const int l15  = lane & 15;
    const int quad = lane >> 4;
    const int wr = wid >> 1, wc = wid & 1;
    const int m0 = blockIdx.x * 128;
    const int n0 = blockIdx.y * 128;

    const int row = tid >> 3, c8s = (tid & 7) << 3;   // 8-u16 chunk coords

    f32x4 acc[4][4];
#pragma unroll
    for (int mi = 0; mi < 4; ++mi)
#pragma unroll
        for (int ni = 0; ni < 4; ++ni)
            acc[mi][ni] = (f32x4){0.f, 0.f, 0.f, 0.f};

    float4 pa[4][2], pb[4][2];
#pragma unroll
    for (int it = 0; it < 4; ++it) {
        size_t ga = (size_t)(m0 + row + 32 * it) * CDIM + c8s;
        size_t gb = (size_t)(n0 + row + 32 * it) * CDIM + c8s;
        pa[it][0] = *(const float4*)&Xf[ga];
        pa[it][1] = *(const float4*)&Xf[ga + 4];
        pb[it][0] = *(const float4*)&Wf[gb];
        pb[it][1] = *(const float4*)&Wf[gb + 4];
    }

    for (int kt = 0; kt < CDIM; kt += 64) {
        __syncthreads();
#pragma unroll
        for (int it = 0; it < 4; ++it) {
            *(uint4*)&As[(row + 32 * it) * LSTR + c8s] =
                pack8(pa[it][0], pa[it][1]);
            *(uint4*)&Bs[(row + 32 * it) * LSTR + c8s] =
                pack8(pb[it][0], pb[it][1]);
        }
        __syncthreads();

        if (kt + 64 < CDIM) {
#pragma unroll
            for (int it = 0; it < 4; ++it) {
                size_t ga = (size_t)(m0 + row + 32 * it) * CDIM + kt + 64 + c8s;
                size_t gb = (size_t)(n0 + row + 32 * it) * CDIM + kt + 64 + c8s;
                pa[it][0] = *(const float4*)&Xf[ga];
                pa[it][1] = *(const float4*)&Xf[ga + 4];
                pb[it][0] = *(const float4*)&Wf[gb];
                pb[it][1] = *(const float4*)&Wf[gb + 4];
            }
        }

#pragma unroll
        for (int k = 0; k < 2; ++k) {
            bf16x8 af[4];
#pragma unroll
            for (int mi = 0; mi < 4; ++mi)
                af[mi] = *(const bf16x8*)
                    &As[(wr * 64 + mi * 16 + l15) * LSTR + quad * 8 + 32 * k];
#pragma unroll
            for (int ni = 0; ni < 4; ++ni) {
                bf16x8 bfr = *(const bf16x8*)
                    &Bs[(wc * 64 + ni * 16 + l15) * LSTR + quad * 8 + 32 * k];
#pragma unroll
                for (int mi = 0; mi < 4; ++mi)
                    acc[mi][ni] = __builtin_amdgcn_mfma_f32_16x16x32_bf16(
                        af[mi], bfr, acc[mi][ni], 0, 0, 0);
            }
        }
    }

    __syncthreads();   // all waves done reading As/Bs before overlay

    // Epilogue. C-layout: token row = wr*64+mi*16+quad*4+r,
    // feature col = wc*64+ni*16+l15. Wave's 64 cols = exactly one head.
    const int bi      = m0 >> 11;
    const int nbase   = (m0 & 2047) + wr * 64;
    const int colbase = n0 + wc * 64;
    const int sel     = colbase / CDIM;          // 0=q,1=k,2=v (wave-uniform)
    const int h       = (colbase % CDIM) >> 6;

    u16* Ew = S + wid * 64 * LSTR;     // wave-private 64x72 tile
    const int grow = lane >> 3;        // copy-out: 8 lanes cover one 128B row
    const int gc8  = (lane & 7) << 3;

    if (sel == 2) {
#pragma unroll
        for (int ni = 0; ni < 4; ++ni)
#pragma unroll
            for (int mi = 0; mi < 4; ++mi)
#pragma unroll
                for (int r = 0; r < 4; ++r)
                    Ew[(ni * 16 + l15) * LSTR + mi * 16 + quad * 4 + r] =
                        f2bf(acc[mi][ni][r]);
        u16* dst = Vb + (size_t)(bi * NH + h) * HD * NSEQ;   // [64][2048]
#pragma unroll
        for (int it = 0; it < 8; ++it) {
            int dd = grow + 8 * it;
            *(uint4*)&dst[(size_t)dd * NSEQ + nbase + gc8] =
                *(const uint4*)&Ew[dd * LSTR + gc8];
        }
    } else {
        u16* dst = ((sel == 0) ? Qb : Kb) + (size_t)(bi * NH + h) * NSEQ * HD;
        const float scl = (sel == 0) ? 0.125f : 1.0f;
#pragma unroll
        for (int ni = 0; ni < 4; ++ni) {
            int dd = ni * 16 + l15;
            float invf = expf(-0.14391156831212787f * (float)(dd & ~1));
#pragma unroll
            for (int mi = 0; mi < 4; ++mi) {
                f32x4 val = acc[mi][ni];
#pragma unroll
                for (int r = 0; r < 4; ++r) {
                    float e = val[r] * scl;
                    float p = __shfl_xor(e, 1);    // pair partner (col^1)
                    int n = nbase + mi * 16 + quad * 4 + r;
                    float sv, cv;
                    __sincosf((float)n * invf, &sv, &cv);
                    float o = (dd & 1) ? (e * cv + p * sv)
                                       : (e * cv - p * sv);
                    Ew[(mi * 16 + quad * 4 + r) * LSTR + dd] = f2bf(o);
                }
            }
        }
#pragma unroll
        for (int it = 0; it < 8; ++it) {
            int tr = grow + 8 * it;
            *(uint4*)&dst[(size_t)(nbase + tr) * HD + gc8] =
                *(const uint4*)&Ew[tr * LSTR + gc8];
        }
    }
}

// ---------------------------------------------------------------------------
// Kernel 2: flash attention, bf16 MFMA. S^T orientation, fixed-max softmax.
// R9: (a) K/V staged with global_load_lds width=16 into LINEAR [64][64]
// LDS rows; the bank-conflict fix is an XOR swizzle (col ^ ((row&7)<<3))
// applied to the GLOBAL source chunk (inverse-swz source) and to every
// LDS read — same involution both sides (guide rule 21).
// (b) LDS 46->40KB -> 4 blocks/CU (was 3).
// (c) Softmax denominator via ones-fragment MFMA (lacc = P @ 1) — replaces
// 16 VALU adds/iter + the end shuffle reduce; layout matches O rows.
// (d) P packed with v_cvt_pk_bf16_f32 (convertvector), not manual f2bf.
// (e) Q fragments read directly from global (one-time, L2-resident).
// Single barrier per key-tile; __syncthreads drains the async loads.
// ---------------------------------------------------------------------------
#define STAGE_KV(BUF, kt_) do {                                               \
    GLD16(Kg + ((size_t)(((kt_) << 6) + r0) * HD + cs),                       \
          &Ks[BUF][wid * 512]);                                               \
    GLD16(Kg + ((size_t)(((kt_) << 6) + r0 + 32) * HD + cs),                  \
          &Ks[BUF][wid * 512 + 2048]);                                        \
    GLD16(Vg + ((size_t)r0 * NSEQ + ((kt_) << 6) + cs),                       \
          &Vs[BUF][wid * 512]);                                               \
    GLD16(Vg + ((size_t)(r0 + 32) * NSEQ + ((kt_) << 6) + cs),                \
          &Vs[BUF][wid * 512 + 2048]);                                        \
} while (0)

#define ATTN_STEP(kt_, CUR, NXT) do {                                         \
    if ((kt_) + 1 < NSEQ / 64) STAGE_KV(NXT, (kt_) + 1);                      \
    f32x4 sacc[4];                                                            \
    _Pragma("unroll")                                                         \
    for (int mt = 0; mt < 4; ++mt) sacc[mt] = (f32x4){0.f, 0.f, 0.f, 0.f};    \
    _Pragma("unroll")                                                         \
    for (int k = 0; k < 2; ++k) {                                             \
        _Pragma("unroll")                                                     \
        for (int mt = 0; mt < 4; ++mt) {                                      \
            bf16x8 ak = *(const bf16x8*)                                      \
                &Ks[CUR][(mt * 16 + l15) * 64 + ((quad * 8 + 32 * k) ^ swz)]; \
            sacc[mt] = __builtin_amdgcn_mfma_f32_16x16x32_bf16(               \
                ak, aq[k], sacc[mt], 0, 0, 0);                                \
        }                                                                     \
    }                                                                         \
    _Pragma("unroll")                                                         \
    for (int mt = 0; mt < 4; ++mt) {                                          \
        f32x4 ev;                                                             \
        _Pragma("unroll")                                                     \
        for (int r = 0; r < 4; ++r) ev[r] = __expf(sacc[mt][r]);              \
        bf16x4t pbk = __builtin_convertvector(ev, bf16x4t);                   \
        *(bf16x4t*)&Pw[l15 * 64 + ((mt * 16 + quad * 4) ^ swz)] = pbk;        \
    }                                                                         \
    _Pragma("unroll")                                                         \
    for (int k = 0; k < 2; ++k) {                                             \
        bf16x8 ap = *(const bf16x8*)                                          \
            &Pw[l15 * 64 + ((quad * 8 + 32 * k) ^ swz)];                      \
        lacc = __builtin_amdgcn_mfma_f32_16x16x32_bf16(                       \
            ap, vone, lacc, 0, 0, 0);                                         \
        _Pragma("unroll")                                                     \
        for (int t = 0; t < 4; ++t) {                                         \
            bf16x8 bv = *(const bf16x8*)                                      \
                &Vs[CUR][(t * 16 + l15) * 64 + ((quad * 8 + 32 * k) ^ swz)];  \
            O[t] = __builtin_amdgcn_mfma_f32_16x16x32_bf16(                   \
                ap, bv, O[t], 0, 0, 0);                                       \
        }                                                                     \
    }                                                                         \
    __syncthreads();                                                          \
} while (0)

__global__ __launch_bounds__(256)
void attn_kernel(const u16* __restrict__ Qb, const u16* __restrict__ Kb,
                 const u16* __restrict__ Vt, u16* __restrict__ AO)
{
    __shared__ __align__(16) u16 Ks[2][64 * 64];
    __shared__ __align__(16) u16 Vs[2][64 * 64];
    __shared__ __align__(16) u16 Ps[4][16 * 64];   // wave-private P tiles

    const int tid  = threadIdx.x;
    const int lane = tid & 63;
    const int wid  = tid >> 6;
    const int l15  = lane & 15;
    const int quad = lane >> 4;
    const int swz  = (l15 & 7) << 3;   // XOR swizzle for frag reads/P writes
    const int qt = blockIdx.x;      // 0..31
    const int bh = blockIdx.y;      // 0..23

    const u16* Qg = Qb + ((size_t)bh * NSEQ + qt * 64) * HD;
    const u16* Kg = Kb + (size_t)bh * NSEQ * HD;
    const u16* Vg = Vt + (size_t)bh * HD * NSEQ;   // [64][2048]

    // staging geometry: 512 16B-chunks per 64x64 tile; thread covers chunks
    // tid and tid+256 (rows r0, r0+32 — same row&7, so same source swizzle)
    const int r0 = tid >> 3;
    const int cs = ((tid & 7) ^ (r0 & 7)) << 3;    // inverse-swizzled src col

    // Q fragments straight from global (rows are 128B; one-time read)
    bf16x8 aq[2];
    aq[0] = *(const bf16x8*)&Qg[(wid * 16 + l15) * HD + quad * 8];
    aq[1] = *(const bf16x8*)&Qg[(wid * 16 + l15) * HD + quad * 8 + 32];

    union { u16 s[8]; bf16x8 v; } oneu;
#pragma unroll
    for (int i = 0; i < 8; ++i) oneu.s[i] = 0x3f80;   // bf16 1.0
    const bf16x8 vone = oneu.v;

    f32x4 O[4];
#pragma unroll
    for (int t = 0; t < 4; ++t) O[t] = (f32x4){0.f, 0.f, 0.f, 0.f};
    f32x4 lacc = (f32x4){0.f, 0.f, 0.f, 0.f};   // softmax denominator rows

    u16* Pw = Ps[wid];

    STAGE_KV(0, 0);
    __syncthreads();

    for (int kt = 0; kt < NSEQ / 64; kt += 2) {
        ATTN_STEP(kt, 0, 1);
        ATTN_STEP(kt + 1, 1, 0);
    }

    // lacc[r] = sum_k P for qrow quad*4+r — same row layout as O[t][r]
    float inv4[4];
#pragma unroll
    for (int r = 0; r < 4; ++r) inv4[r] = 1.0f / lacc[r];

    const int b = bh / NH, h = bh % NH;
#pragma unroll
    for (int r = 0; r < 4; ++r) {
        size_t row = (size_t)b * NSEQ + qt * 64 + wid * 16 + quad * 4 + r;
#pragma unroll
        for (int t = 0; t < 4; ++t)
            AO[row * CDIM + h * HD + t * 16 + l15] = f2bf(O[t][r] * inv4[r]);
    }
}

// ---------------------------------------------------------------------------
// Kernel 3: out = AO @ Wproj^T + bias, bf16 MFMA. R9: retiled 128x128 ->
// 64x64 so grid goes (32,6)=192 blocks (0.75/CU, 1 wave/SIMD, zero latency
// hiding) -> (64,12)=768 blocks (3/CU). A staged via global_load_lds with
// source-side XOR swizzle; W converted fp32->bf16 with cvt_pk during staging.
// ---------------------------------------------------------------------------
__global__ __launch_bounds__(256)
void proj_kernel(const u16* __restrict__ A, const float* __restrict__ Wf,
                 const float* __restrict__ bias, float* __restrict__ out)
{
    __shared__ __align__(16) u16 As[64 * 64];
    __shared__ __align__(16) u16 Bs[64 * 64];
    const int tid  = threadIdx.x;
    const int lane = tid & 63;
    const int wid  = tid >> 6;
    const int l15  = lane & 15;
    const int quad = lane >> 4;
    const int swz  = (l15 & 7) << 3;
    const int wr = wid >> 1, wc = wid & 1;
    const int m0 = blockIdx.x * 64;
    const int n0 = blockIdx.y * 64;

    const int r0 = tid >> 3;                        // 0..31
    const int cs = ((tid & 7) ^ (r0 & 7)) << 3;     // swizzled A source col
    const int c8 = (tid & 7) << 3;
    const int bswz = c8 ^ ((r0 & 7) << 3);          // swizzled B dest col

    f32x4 acc[2][2];
#pragma unroll
    for (int mi = 0; mi < 2; ++mi)
#pragma unroll
        for (int ni = 0; ni < 2; ++ni)
            acc[mi][ni] = (f32x4){0.f, 0.f, 0.f, 0.f};

    for (int kt = 0; kt < CDIM; kt += 64) {
        __syncthreads();
        // A: 64x64 bf16 tile, async direct-to-LDS (chunks tid, tid+256)
        GLD16(A + ((size_t)(m0 + r0) * CDIM + kt + cs),      &As[wid * 512]);
        GLD16(A + ((size_t)(m0 + r0 + 32) * CDIM + kt + cs), &As[wid * 512 + 2048]);
        // B: 64x64 fp32 -> bf16, swizzled register-staged write
        {
            size_t gb0 = (size_t)(n0 + r0) * CDIM + kt + c8;
            size_t gb1 = (size_t)(n0 + r0 + 32) * CDIM + kt + c8;
            float4 w0 = *(const float4*)&Wf[gb0];
            float4 w1 = *(const float4*)&Wf[gb0 + 4];
            float4 w2 = *(const float4*)&Wf[gb1];
            float4 w3 = *(const float4*)&Wf[gb1 + 4];
            *(uint4*)&Bs[r0 * 64 + bswz]        = pack8(w0, w1);
            *(uint4*)&Bs[(r0 + 32) * 64 + bswz] = pack8(w2, w3);
        }
        __syncthreads();

#pragma unroll
        for (int k = 0; k < 2; ++k) {
            bf16x8 af[2], bf[2];
#pragma unroll
            for (int mi = 0; mi < 2; ++mi)
                af[mi] = *(const bf16x8*)
                    &As[(wr * 32 + mi * 16 + l15) * 64 + ((quad * 8 + 32 * k) ^ swz)];
#pragma unroll
            for (int ni = 0; ni < 2; ++ni)
                bf[ni] = *(const bf16x8*)
                    &Bs[(wc * 32 + ni * 16 + l15) * 64 + ((quad * 8 + 32 * k) ^ swz)];
#pragma unroll
            for (int mi = 0; mi < 2; ++mi)
#pragma unroll
                for (int ni = 0; ni < 2; ++ni)
                    acc[mi][ni] = __builtin_amdgcn_mfma_f32_16x16x32_bf16(
                        af[mi], bf[ni], acc[mi][ni], 0, 0, 0);
        }
    }

#pragma unroll
    for (int ni = 0; ni < 2; ++ni) {
        int col = n0 + wc * 32 + ni * 16 + l15;
        float bb = bias[col];
#pragma unroll
        for (int mi = 0; mi < 2; ++mi) {
            int row = m0 + wr * 32 + mi * 16 + quad * 4;
#pragma unroll
            for (int r = 0; r < 4; ++r)
                out[(size_t)(row + r) * CDIM + col] = acc[mi][ni][r] + bb;
        }
    }
}

// ---------------------------------------------------------------------------
extern "C" void kernel_launch(void* const* d_in, const int* in_sizes, int n_in,
                              void* d_out, int out_size, void* d_ws,
                              size_t ws_size, hipStream_t stream)
{
    const float* X     = (const float*)d_in[0];   // [2, 2048, 768]
    const float* Wqkv  = (const float*)d_in[1];   // [2304, 768]
    const float* Wproj = (const float*)d_in[2];   // [768, 768]
    const float* bias  = (const float*)d_in[3];   // [768]
    float* out = (float*)d_out;                   // [2, 2048, 768]

    const size_t per_buf = (size_t)NB * NH * NSEQ * HD;   // 3145728
    u16* Qb  = (u16*)d_ws;
    u16* Kb  = Qb + per_buf;
    u16* Vb  = Kb + per_buf;                      // [B,H,64,N]
    u16* AOb = Vb + per_buf;                      // [4096, 768] bf16

    qkv_mfma_kernel<<<dim3(32, 18), 256, 0, stream>>>(X, Wqkv, Qb, Kb, Vb);
    attn_kernel<<<dim3(32, 24), 256, 0, stream>>>(Qb, Kb, Vb, AOb);
    proj_kernel<<<dim3(64, 12), 256, 0, stream>>>(AOb, Wproj, bias, out);
}